// Round 1
// 548.543 us; speedup vs baseline: 1.0036x; 1.0036x over previous
//
#include <hip/hip_runtime.h>

// Linear_AB_I8_DE_F32: y[m,n] = 0.01 * sum_k x8[m,k]*w8[n,k] + bias[n]
// M=4096, N=11008, K=4096. int8 values in int32 containers.
//
// R4: port to the 256x256 8-phase counted-vmcnt template (T3+T4+T5 + T1):
//   - BM=BN=256, BK=128B, 8 waves (512 thr), 128 KiB double-buffered LDS
//   - 4 phases/K-tile: {ds_read subtile | stage half-tile | s_barrier |
//     setprio(1) 16xMFMA setprio(0) | s_barrier}; raw s_barrier (no
//     __syncthreads -> no vmcnt(0) drain in the main loop)
//   - steady-state s_waitcnt vmcnt(4) once per K-tile, never 0
//   - XOR swizzle widened to 8 chunks/row: pos = chunk ^ (row&7), applied
//     inverse on the global source (linear global_load_lds dest)
//   - bijective XCD swizzle: 688 blocks = 8 XCDs x 86; each XCD owns 2
//     M-panels (2MB, L2-resident), B-panel-sharing blocks paired.

#define M_DIM 4096
#define N_DIM 11008
#define K_DIM 4096
#define BM 256
#define BN 256
#define BK 128                  // bytes of K per tile (int8)
#define NT (K_DIM / BK)         // 32 K-tiles
#define ALPHA 0.01f

typedef __attribute__((ext_vector_type(4))) int i32x4;

static __device__ __forceinline__ int pack4(int4 v) {
    return (v.x & 0xff) | ((v.y & 0xff) << 8) |
           ((v.z & 0xff) << 16) | ((unsigned)(v.w & 0xff) << 24);
}

// ---------------- fused pack: 16 int32 -> 16 int8 per thread ----------------
__global__ __launch_bounds__(256) void pack_i8_kernel(
    const int4* __restrict__ x, int4* __restrict__ xout, int n16x,
    const int4* __restrict__ w, int4* __restrict__ wout, int n16_total)
{
    int i = blockIdx.x * blockDim.x + threadIdx.x;
    if (i >= n16_total) return;
    const int4* src;
    int4* dst;
    int idx;
    if (i < n16x) { src = x; dst = xout; idx = i; }
    else          { src = w; dst = wout; idx = i - n16x; }
    const int4* p = src + (size_t)4 * idx;
    int4 a = p[0], b = p[1], c = p[2], d = p[3];
    int4 r;
    r.x = pack4(a); r.y = pack4(b); r.z = pack4(c); r.w = pack4(d);
    dst[idx] = r;
}

// ---------------- GEMM ----------------
#define GLOAD_LDS16(g, l) __builtin_amdgcn_global_load_lds(                   \
    (const __attribute__((address_space(1))) void*)(g),                       \
    (__attribute__((address_space(3))) void*)(l), 16, 0, 0)

#define MFMA_Q(mh, nh, aq, bq)                                                \
    __builtin_amdgcn_s_setprio(1);                                            \
    _Pragma("unroll")                                                         \
    for (int i_ = 0; i_ < 4; i_++)                                            \
        _Pragma("unroll")                                                     \
        for (int j_ = 0; j_ < 2; j_++)                                        \
            _Pragma("unroll")                                                 \
            for (int k_ = 0; k_ < 2; k_++)                                    \
                acc[(mh) * 4 + i_][(nh) * 2 + j_] =                           \
                    __builtin_amdgcn_mfma_i32_16x16x64_i8(                    \
                        aq[i_][k_], bq[j_][k_],                               \
                        acc[(mh) * 4 + i_][(nh) * 2 + j_], 0, 0, 0);          \
    __builtin_amdgcn_s_setprio(0);

__global__ __launch_bounds__(512, 2) void gemm_i8_kernel(
    const char* __restrict__ A,     // [M][K] int8 row-major
    const char* __restrict__ B,     // [N][K] int8 row-major
    const float* __restrict__ bias, // [N]
    float* __restrict__ C)          // [M][N] fp32
{
    __shared__ __attribute__((aligned(16))) char As[2][BM * BK]; // 2 x 32 KB
    __shared__ __attribute__((aligned(16))) char Bs[2][BN * BK]; // 2 x 32 KB

    const int tid   = threadIdx.x;
    const int lane  = tid & 63;
    const int wave  = tid >> 6;
    const int waveM = (wave >> 2) * 128;   // 2x4 wave grid: 128x64 per wave
    const int waveN = (wave & 3) * 64;
    const int lrow  = lane & 15;
    const int lquad = lane >> 4;

    // bijective XCD swizzle: 688 = 8 * 86. XCD x owns M-panels {2x, 2x+1};
    // consecutive local pairs share a B-panel (concurrent L2 reuse).
    const int bid = blockIdx.x;
    const int xcd = bid & 7;
    const int loc = bid >> 3;              // 0..85
    const int bm  = (2 * xcd + (loc & 1)) * BM;
    const int bn  = (loc >> 1) * BN;

    // staging: thread tid covers 16B slot tid of a 64-row chunk (8 slots/row).
    // LDS slot (row, pos) holds global chunk pos ^ (row&7)  ->  inverse-swizzle
    // the global source, keep global_load_lds dest linear.
    const int srow = tid >> 3;
    const int schk = ((tid & 7) ^ (srow & 7)) << 4;
    const char* Asrc = A + (size_t)(bm + srow) * K_DIM + schk;
    const char* Bsrc = B + (size_t)(bn + srow) * K_DIM + schk;

    // frag read: global chunk (ks*4+lquad) of row r is at pos (ks*4+lquad)^(r&7);
    // r&7 == lrow&7 for 16-aligned tile bases. Every 8-lane group covers all
    // 8 bank slots -> conflict-free ds_read_b128.
    int aoff[2], boff[2];
#pragma unroll
    for (int ks = 0; ks < 2; ks++) {
        const int pos = ((ks * 4 + lquad) ^ (lrow & 7)) << 4;
        aoff[ks] = (waveM + lrow) * BK + pos;
        boff[ks] = (waveN + lrow) * BK + pos;
    }

    i32x4 acc[8][4] = {};

    auto stage_a = [&](int buf, int t, int half) {
        GLOAD_LDS16(Asrc + (size_t)(half * 128) * K_DIM + t * BK,
                    &As[buf][half * 16384 + tid * 16]);
        GLOAD_LDS16(Asrc + (size_t)(half * 128 + 64) * K_DIM + t * BK,
                    &As[buf][half * 16384 + 8192 + tid * 16]);
    };
    auto stage_b = [&](int buf, int t, int half) {
        GLOAD_LDS16(Bsrc + (size_t)(half * 128) * K_DIM + t * BK,
                    &Bs[buf][half * 16384 + tid * 16]);
        GLOAD_LDS16(Bsrc + (size_t)(half * 128 + 64) * K_DIM + t * BK,
                    &Bs[buf][half * 16384 + 8192 + tid * 16]);
    };

    // prologue: tile0 fully (8 loads) + tile1 A (4 loads); wait tile0 only.
    stage_a(0, 0, 0); stage_a(0, 0, 1);
    stage_b(0, 0, 0); stage_b(0, 0, 1);
    stage_a(1, 1, 0); stage_a(1, 1, 1);
    asm volatile("s_waitcnt vmcnt(4)" ::: "memory");
    __builtin_amdgcn_s_barrier();

    for (int g = 0; g < NT; ++g) {
        const int cur = g & 1;
        const char* Ac = As[cur];
        const char* Bc = Bs[cur];
        i32x4 a0[4][2], a1[4][2], b01[2][2], b23[2][2];

        // ---- P1: read a0..3 + b0..1; stage (g+1).B half0 -> buf cur^1
#pragma unroll
        for (int i = 0; i < 4; i++)
#pragma unroll
            for (int ks = 0; ks < 2; ks++)
                a0[i][ks] = *(const i32x4*)(Ac + aoff[ks] + i * 2048);
#pragma unroll
        for (int j = 0; j < 2; j++)
#pragma unroll
            for (int ks = 0; ks < 2; ks++)
                b01[j][ks] = *(const i32x4*)(Bc + boff[ks] + j * 2048);
        if (g + 1 < NT) { stage_b(cur ^ 1, g + 1, 0); }
        __builtin_amdgcn_s_barrier();
        MFMA_Q(0, 0, a0, b01);
        __builtin_amdgcn_s_barrier();

        // ---- P2: read b2..3; stage (g+1).B half1
#pragma unroll
        for (int j = 0; j < 2; j++)
#pragma unroll
            for (int ks = 0; ks < 2; ks++)
                b23[j][ks] = *(const i32x4*)(Bc + boff[ks] + (j + 2) * 2048);
        if (g + 1 < NT) { stage_b(cur ^ 1, g + 1, 1); }
        __builtin_amdgcn_s_barrier();
        MFMA_Q(0, 1, a0, b23);
        __builtin_amdgcn_s_barrier();

        // ---- P3: read a4..7 (releases A of buf cur at the end barrier)
#pragma unroll
        for (int i = 0; i < 4; i++)
#pragma unroll
            for (int ks = 0; ks < 2; ks++)
                a1[i][ks] = *(const i32x4*)(Ac + aoff[ks] + (i + 4) * 2048);
        __builtin_amdgcn_s_barrier();
        MFMA_Q(1, 1, a1, b23);
        __builtin_amdgcn_s_barrier();

        // ---- P4: re-read b0..1; stage (g+2).A into released half of buf cur;
        //          counted vmcnt (never 0 in steady state)
#pragma unroll
        for (int j = 0; j < 2; j++)
#pragma unroll
            for (int ks = 0; ks < 2; ks++)
                b01[j][ks] = *(const i32x4*)(Bc + boff[ks] + j * 2048);
        if (g + 2 < NT) {
            stage_a(cur, g + 2, 0); stage_a(cur, g + 2, 1);
            asm volatile("s_waitcnt vmcnt(4)" ::: "memory");
        } else {
            asm volatile("s_waitcnt vmcnt(0)" ::: "memory");
        }
        __builtin_amdgcn_s_barrier();
        MFMA_Q(1, 0, a1, b01);
        __builtin_amdgcn_s_barrier();
    }

    // epilogue: C/D layout col=lane&15, row=(lane>>4)*4+reg
#pragma unroll
    for (int i = 0; i < 8; i++) {
        const int r0 = bm + waveM + i * 16 + lquad * 4;
#pragma unroll
        for (int j = 0; j < 4; j++) {
            const int c0 = bn + waveN + j * 16 + lrow;
            const float bv = bias[c0];
#pragma unroll
            for (int r = 0; r < 4; r++) {
                C[(size_t)(r0 + r) * N_DIM + c0] = ALPHA * (float)acc[i][j][r] + bv;
            }
        }
    }
}

extern "C" void kernel_launch(void* const* d_in, const int* in_sizes, int n_in,
                              void* d_out, int out_size, void* d_ws, size_t ws_size,
                              hipStream_t stream) {
    const int*   x    = (const int*)d_in[0];
    const int*   w    = (const int*)d_in[1];
    const float* bias = (const float*)d_in[2];
    float*       out  = (float*)d_out;

    char* Ap = (char*)d_ws;
    char* Wp = (char*)d_ws + (size_t)M_DIM * K_DIM;

    const int n16x = M_DIM * K_DIM / 16;          // 1,048,576
    const int n16w = N_DIM * K_DIM / 16;          // 2,818,048
    const int n16  = n16x + n16w;                 // 3,866,624 -> 15104 blocks
    pack_i8_kernel<<<n16 / 256, 256, 0, stream>>>(
        (const int4*)x, (int4*)Ap, n16x, (const int4*)w, (int4*)Wp, n16);

    // 688 blocks = 8 XCDs x 86 (bijective swizzle inside the kernel)
    gemm_i8_kernel<<<dim3((M_DIM / BM) * (N_DIM / BN)), 512, 0, stream>>>(
        Ap, Wp, bias, out);
}